// Round 11
// baseline (780.678 us; speedup 1.0000x reference)
//
#include <hip/hip_runtime.h>
#include <hip/hip_bf16.h>

// Pattention fused kernel, round 9: 32x32 GEMM1 (2 A-waves, X streamed from L2),
// K staging moved to B-team, full-row ^(r&31) LDS swizzle (2-way free reads).
// 384-thread blocks: waves 0-1 = Team A (GEMM1+GELU), waves 2-5 = Team B (GEMM2+staging).
// out[m,n] = (sqrt(P)/||gelu(X K^T)[m,:]||) * (gelu(X K^T) @ V)[m,n]
// M=16384 (B*T), D=512, P=4096. bf16 MFMA, fp32 accum.

typedef __attribute__((ext_vector_type(8)))  short bf16x8;   // 8 bf16 = 4 VGPR
typedef __attribute__((ext_vector_type(4)))  float f32x4;    // 16x16 C/D
typedef __attribute__((ext_vector_type(16))) float f32x16;   // 32x32 C/D

static constexpr int M_TOTAL = 16384;
static constexpr int DDIM    = 512;
static constexpr int PDIM    = 4096;
static constexpr int BM      = 64;    // rows per block
static constexpr int BP      = 64;    // P-tile
static constexpr int NSLOT   = PDIM / BP;   // 64
static constexpr int GPAD    = 72;    // g_lds row stride elems (144B)

#define AS1C(p) ((const __attribute__((address_space(1))) void*)(p))
#define AS3(p)  ((__attribute__((address_space(3))) void*)(p))

__device__ __forceinline__ unsigned f2bf(float f) {
    union { float f; unsigned u; } v; v.f = f;
    unsigned r = v.u + 0x7FFFu + ((v.u >> 16) & 1u);   // RNE
    return (r >> 16);
}

// tanh-form GELU: x * sigmoid(2 * x * (c0 + c1 x^2)); |err vs exact| < 1e-3
__device__ __forceinline__ float gelu_f(float x) {
    float t2 = 2.0f * x * (0.7978845608028654f + 0.035677408136300125f * x * x);
    return x / (1.0f + __expf(-t2));
}

// ---------- fp32 -> bf16 row-major (used for K and X) ----------
__global__ void conv_bf(const float* __restrict__ in, unsigned short* __restrict__ outb) {
    int i = (blockIdx.x * 256 + threadIdx.x) * 4;
    float4 v = *reinterpret_cast<const float4*>(in + i);
    ushort4 o;
    o.x = (unsigned short)f2bf(v.x); o.y = (unsigned short)f2bf(v.y);
    o.z = (unsigned short)f2bf(v.z); o.w = (unsigned short)f2bf(v.w);
    *reinterpret_cast<ushort4*>(outb + i) = o;
}

// ---------- value_tokens fp32 [4096][512] -> fragment-blocked bf16 (16x16 B-frags) ----------
//   vt2[ ((pb*32 + nb)*64 + lane)*8 + j ] = V[ pb*32 + (lane>>4)*8 + j ][ nb*16 + (lane&15) ]
__global__ void conv_vt2(const float* __restrict__ vin, unsigned short* __restrict__ vt2) {
    int tid  = blockIdx.x * 256 + threadIdx.x;  // 262144 total
    int lane = tid & 63;
    int blk  = tid >> 6;
    int nb = blk & 31;
    int pb = blk >> 5;
    int p0 = pb * 32 + ((lane >> 4) << 3);
    int n  = nb * 16 + (lane & 15);
    ushort4 a, b;
    a.x = (unsigned short)f2bf(vin[(p0 + 0) * DDIM + n]);
    a.y = (unsigned short)f2bf(vin[(p0 + 1) * DDIM + n]);
    a.z = (unsigned short)f2bf(vin[(p0 + 2) * DDIM + n]);
    a.w = (unsigned short)f2bf(vin[(p0 + 3) * DDIM + n]);
    b.x = (unsigned short)f2bf(vin[(p0 + 4) * DDIM + n]);
    b.y = (unsigned short)f2bf(vin[(p0 + 5) * DDIM + n]);
    b.z = (unsigned short)f2bf(vin[(p0 + 6) * DDIM + n]);
    b.w = (unsigned short)f2bf(vin[(p0 + 7) * DDIM + n]);
    *reinterpret_cast<ushort4*>(vt2 + tid * 8 + 0) = a;
    *reinterpret_cast<ushort4*>(vt2 + tid * 8 + 4) = b;
}

// ---------- fused kernel: 256 blocks x 384 threads (2 A-waves + 4 B-waves) ----------
__global__ __launch_bounds__(384, 1) void fused_pattn(
    const unsigned short* __restrict__ xbf,   // [16384][512] bf16
    const unsigned short* __restrict__ kbf,   // [4096][512] bf16
    const unsigned short* __restrict__ vt2,   // fragment-blocked bf16
    float* __restrict__ out)                  // [16384][512] fp32
{
    // k_lds: [64][512] bf16 per buffer, chunk-swizzled: LDS chunk c of row r holds
    // global chunk c ^ (r&31)  (chunk = 16B). Staged via pre-swizzled DMA source.
    __shared__ unsigned short k_lds[2][BP * DDIM];   // 2 x 65536 B
    __shared__ unsigned short g_lds[2][BM * GPAD];   // 2 x  9216 B
    __shared__ float ss_lds[BM];                     // 256 B   (~149.8 KB)

    const int tid  = threadIdx.x;
    const int lane = tid & 63;
    const int w    = tid >> 6;       // wave 0..5
    const int l15  = lane & 15;
    const int l4   = lane >> 4;
    const int m_base = blockIdx.x * BM;

    if (w < 2) {
        // ========== TEAM A: GEMM1 (32x32x16, swapped -> S^T) + GELU ==========
        // Wave w owns m-rows [w*32, w*32+32), all 64 p. No staging, no X residency.
        const int l31 = lane & 31;
        const int lh  = lane >> 5;

        // X stream base: lane reads X[m_base + w*32 + l31][ds*16 + lh*8 .. +8]
        unsigned long long xa =
            (unsigned long long)(xbf + (size_t)(m_base + w * 32 + l31) * DDIM + lh * 8);

        float ss = 0.0f;
        __builtin_amdgcn_s_barrier();                       // bar_0 (k(0) staged by B)

        #pragma unroll 1
        for (int t = 0; t < NSLOT; ++t) {
            // keep xv loads inside the loop (prevent 128-reg hoist)
            asm volatile("" : "+v"(xa));
            const unsigned short* xr = (const unsigned short*)xa;

            f32x16 s0, s1;
            #pragma unroll
            for (int j = 0; j < 16; ++j) { s0[j] = 0.0f; s1[j] = 0.0f; }

            const unsigned short* kb = &k_lds[t & 1][0];
            __builtin_amdgcn_s_setprio(1);
            #pragma unroll
            for (int ds = 0; ds < 32; ++ds) {
                int ce = (((ds * 2 + lh) ^ l31) << 3);      // swizzled elem offset
                bf16x8 kv0 = *reinterpret_cast<const bf16x8*>(kb + l31 * DDIM + ce);
                bf16x8 kv1 = *reinterpret_cast<const bf16x8*>(kb + (32 + l31) * DDIM + ce);
                bf16x8 xv  = *reinterpret_cast<const bf16x8*>(xr + ds * 16);
                s0 = __builtin_amdgcn_mfma_f32_32x32x16_bf16(kv0, xv, s0, 0, 0, 0);
                s1 = __builtin_amdgcn_mfma_f32_32x32x16_bf16(kv1, xv, s1, 0, 0, 0);
            }
            __builtin_amdgcn_s_setprio(0);

            // GELU + lane-local sumsq + packed b64 writes.
            // 32x32 C/D: col(=m within block) = l31, row(=p) = (reg&3) + 8*(reg>>2) + 4*lh.
            unsigned short* gb = &g_lds[t & 1][0];
            const int m_l = w * 32 + l31;
            const int pb_lh = lh * 4;
            #pragma unroll
            for (int q = 0; q < 4; ++q) {
                float g0 = gelu_f(s0[4 * q + 0]);
                float g1 = gelu_f(s0[4 * q + 1]);
                float g2 = gelu_f(s0[4 * q + 2]);
                float g3 = gelu_f(s0[4 * q + 3]);
                ss += g0 * g0 + g1 * g1 + g2 * g2 + g3 * g3;
                unsigned d0 = f2bf(g0) | (f2bf(g1) << 16);
                unsigned d1 = f2bf(g2) | (f2bf(g3) << 16);
                *reinterpret_cast<uint2*>(&gb[m_l * GPAD + q * 8 + pb_lh]) = make_uint2(d0, d1);
            }
            #pragma unroll
            for (int q = 0; q < 4; ++q) {
                float g0 = gelu_f(s1[4 * q + 0]);
                float g1 = gelu_f(s1[4 * q + 1]);
                float g2 = gelu_f(s1[4 * q + 2]);
                float g3 = gelu_f(s1[4 * q + 3]);
                ss += g0 * g0 + g1 * g1 + g2 * g2 + g3 * g3;
                unsigned d0 = f2bf(g0) | (f2bf(g1) << 16);
                unsigned d1 = f2bf(g2) | (f2bf(g3) << 16);
                *reinterpret_cast<uint2*>(&gb[m_l * GPAD + 32 + q * 8 + pb_lh]) =
                    make_uint2(d0, d1);
            }
            asm volatile("s_waitcnt lgkmcnt(0)" ::: "memory");
            __builtin_amdgcn_s_barrier();                   // bar_{t+1}
        }

        // each lane has 32 of the 64 p per m-row; partner lane (^32) has the rest
        ss += __shfl_xor(ss, 32, 64);
        if (lane < 32) ss_lds[w * 32 + l31] = ss;
        asm volatile("s_waitcnt lgkmcnt(0)" ::: "memory");
        __builtin_amdgcn_s_barrier();                       // bar_{NSLOT+1}
    } else {
        // ========== TEAM B: GEMM2 (16x16x32) + K staging + epilogue ==========
        const int bw = w - 2;        // owns output cols [bw*128, bw*128+128)

        // ---- prologue: stage k(0), k(1); prefetch bg(0) ----
        #pragma unroll
        for (int i = 0; i < 16; ++i) {
            int r = bw * 16 + i;
            const unsigned short* src = kbf + (size_t)r * DDIM + ((lane ^ (r & 31)) << 3);
            __builtin_amdgcn_global_load_lds(AS1C(src), AS3(&k_lds[0][r * DDIM]), 16, 0, 0);
        }
        __builtin_amdgcn_sched_barrier(0);
        #pragma unroll
        for (int i = 0; i < 16; ++i) {
            int r = bw * 16 + i;
            const unsigned short* src = kbf + (size_t)(BP + r) * DDIM + ((lane ^ (r & 31)) << 3);
            __builtin_amdgcn_global_load_lds(AS1C(src), AS3(&k_lds[1][r * DDIM]), 16, 0, 0);
        }
        __builtin_amdgcn_sched_barrier(0);
        bf16x8 bg[16];
        #pragma unroll
        for (int ks = 0; ks < 2; ++ks)
            #pragma unroll
            for (int nf = 0; nf < 8; ++nf)
                bg[ks * 8 + nf] = *reinterpret_cast<const bf16x8*>(
                    vt2 + ((size_t)(ks * 32 + bw * 8 + nf) * 64 + lane) * 8);
        __builtin_amdgcn_sched_barrier(0);
        asm volatile("s_waitcnt vmcnt(32)" ::: "memory");   // stage(0) landed
        __builtin_amdgcn_s_barrier();                       // bar_0
        asm volatile("s_waitcnt vmcnt(16)" ::: "memory");   // stage(1) landed, bg flying
        __builtin_amdgcn_s_barrier();                       // bar_1

        f32x4 zero4 = {0.0f, 0.0f, 0.0f, 0.0f};
        f32x4 oacc[4][8];
        #pragma unroll
        for (int i = 0; i < 4; ++i)
            #pragma unroll
            for (int j = 0; j < 8; ++j) oacc[i][j] = zero4;

        #pragma unroll 1
        for (int u = 0; u < NSLOT; ++u) {
            // window [bar_{u+1}, bar_{u+2}]: consume g(u), stage k(u+2), prefetch bg(u+1)
            const unsigned short* gb = &g_lds[u & 1][0];
            __builtin_amdgcn_s_setprio(1);
            #pragma unroll
            for (int ks = 0; ks < 2; ++ks) {
                bf16x8 ag[4];
                #pragma unroll
                for (int mf = 0; mf < 4; ++mf)
                    ag[mf] = *reinterpret_cast<const bf16x8*>(
                        &gb[(mf * 16 + l15) * GPAD + ks * 32 + l4 * 8]);
                #pragma unroll
                for (int mf = 0; mf < 4; ++mf)
                    #pragma unroll
                    for (int nf = 0; nf < 8; ++nf)
                        oacc[mf][nf] = __builtin_amdgcn_mfma_f32_16x16x32_bf16(
                            ag[mf], bg[ks * 8 + nf], oacc[mf][nf], 0, 0, 0);
            }
            __builtin_amdgcn_s_setprio(0);

            // stage k(u+2) into k_lds[u&1] (A finished reading it at bar_{u+1})
            {
                const int P0n = ((u + 2) & (NSLOT - 1)) * BP;
                #pragma unroll
                for (int i = 0; i < 16; ++i) {
                    int r = bw * 16 + i;
                    const unsigned short* src =
                        kbf + (size_t)(P0n + r) * DDIM + ((lane ^ (r & 31)) << 3);
                    __builtin_amdgcn_global_load_lds(
                        AS1C(src), AS3(&k_lds[u & 1][r * DDIM]), 16, 0, 0);
                }
            }
            __builtin_amdgcn_sched_barrier(0);
            // prefetch bg(u+1) (wraps on last iter; harmless)
            {
                const int pb0 = ((u + 1) & (NSLOT - 1)) * 2;
                #pragma unroll
                for (int ks = 0; ks < 2; ++ks)
                    #pragma unroll
                    for (int nf = 0; nf < 8; ++nf)
                        bg[ks * 8 + nf] = *reinterpret_cast<const bf16x8*>(
                            vt2 + ((size_t)((pb0 + ks) * 32 + bw * 8 + nf) * 64 + lane) * 8);
            }
            __builtin_amdgcn_sched_barrier(0);
            asm volatile("s_waitcnt vmcnt(16)" ::: "memory");  // stage done, bg flying
            __builtin_amdgcn_s_barrier();                      // bar_{u+2}
        }
        // last barrier above is bar_{NSLOT+1}: ss_lds is ready

        // epilogue: out = O * sqrt(P)/sqrt(ss)
        #pragma unroll
        for (int mf = 0; mf < 4; ++mf) {
            #pragma unroll
            for (int r = 0; r < 4; ++r) {
                int m_l = mf * 16 + l4 * 4 + r;
                float scale = 64.0f * rsqrtf(ss_lds[m_l]);
                float* orow = out + (size_t)(m_base + m_l) * DDIM + bw * 128 + l15;
                #pragma unroll
                for (int nf = 0; nf < 8; ++nf)
                    orow[nf * 16] = oacc[mf][nf][r] * scale;
            }
        }
    }
}

extern "C" void kernel_launch(void* const* d_in, const int* in_sizes, int n_in,
                              void* d_out, int out_size, void* d_ws, size_t ws_size,
                              hipStream_t stream) {
    const float* x = (const float*)d_in[0];   // [4,4096,512] = [16384][512]
    const float* k = (const float*)d_in[1];   // [4096][512]
    const float* v = (const float*)d_in[2];   // [4096][512]
    float* out = (float*)d_out;               // [16384][512]

    unsigned short* kbf = (unsigned short*)d_ws;                  //  4 MB
    unsigned short* vt2 = kbf + (size_t)PDIM * DDIM;              //  4 MB
    unsigned short* xbf = vt2 + (size_t)PDIM * DDIM;              // 16 MB (total 24 MB)

    conv_bf <<<dim3(2048),  dim3(256), 0, stream>>>(k, kbf);
    conv_vt2<<<dim3(1024),  dim3(256), 0, stream>>>(v, vt2);
    conv_bf <<<dim3(8192),  dim3(256), 0, stream>>>(x, xbf);
    fused_pattn<<<dim3(M_TOTAL / BM), dim3(384), 0, stream>>>(xbf, kbf, vt2, out);
}

// Round 12
// 289.958 us; speedup vs baseline: 2.6924x; 2.6924x over previous
//
#include <hip/hip_runtime.h>
#include <hip/hip_bf16.h>

// Pattention fused kernel, round 10: r6 producer/consumer base + AGPR-resident X.
// Team A (waves 0-1): each owns 32 m-rows; X fragments live in AGPR ("a" operand of
//   inline-asm MFMA) -> one kv read feeds 2 MFMAs, halving k_lds read volume.
// Team B (waves 2-5): r6's GEMM2 verbatim (128 cols/wave, oacc[4][8], bg prefetch).
// 384-thread blocks, 256 blocks. 1 barrier/slot, 64 slots.
// out[m,n] = (sqrt(P)/||gelu(X K^T)[m,:]||) * (gelu(X K^T) @ V)[m,n]
// M=16384 (B*T), D=512, P=4096. bf16 MFMA (16x16x32), fp32 accum.

typedef __attribute__((ext_vector_type(8))) short bf16x8;   // 8 bf16 = 4 VGPR
typedef __attribute__((ext_vector_type(4))) int   i32x4;    // 4 VGPR/AGPR (8 bf16)
typedef __attribute__((ext_vector_type(4))) float f32x4;    // MFMA C/D

static constexpr int M_TOTAL = 16384;
static constexpr int DDIM    = 512;
static constexpr int PDIM    = 4096;
static constexpr int BM      = 64;    // rows per block
static constexpr int BP      = 64;    // P-tile
static constexpr int NSLOT   = PDIM / BP;   // 64
static constexpr int GPAD    = 72;    // g_lds row stride elems (144B)

#define AS1C(p) ((const __attribute__((address_space(1))) void*)(p))
#define AS3(p)  ((__attribute__((address_space(3))) void*)(p))

__device__ __forceinline__ unsigned f2bf(float f) {
    union { float f; unsigned u; } v; v.f = f;
    unsigned r = v.u + 0x7FFFu + ((v.u >> 16) & 1u);   // RNE
    return (r >> 16);
}

// tanh-form GELU: x * sigmoid(2 * x * (c0 + c1 x^2)); |err vs exact| < 1e-3
__device__ __forceinline__ float gelu_f(float x) {
    float t2 = 2.0f * x * (0.7978845608028654f + 0.035677408136300125f * x * x);
    return x / (1.0f + __expf(-t2));
}

// MFMA with B-operand pinned to AGPR (xf lives there for its whole range).
__device__ __forceinline__ void mfma_av(f32x4& d, const i32x4& kv, const i32x4& xf) {
    asm("v_mfma_f32_16x16x32_bf16 %0, %1, %2, %0"
        : "+v"(d) : "v"(kv), "a"(xf));
}

// ---------- convert key_tokens fp32 -> bf16 row-major [4096][512] ----------
__global__ void conv_k(const float* __restrict__ kin, unsigned short* __restrict__ kbf) {
    int i = (blockIdx.x * 256 + threadIdx.x) * 4;
    float4 v = *reinterpret_cast<const float4*>(kin + i);
    ushort4 o;
    o.x = (unsigned short)f2bf(v.x); o.y = (unsigned short)f2bf(v.y);
    o.z = (unsigned short)f2bf(v.z); o.w = (unsigned short)f2bf(v.w);
    *reinterpret_cast<ushort4*>(kbf + i) = o;
}

// ---------- value_tokens fp32 [4096][512] -> fragment-blocked bf16 ----------
//   vt2[ ((pb*32 + nb)*64 + lane)*8 + j ] = V[ pb*32 + (lane>>4)*8 + j ][ nb*16 + (lane&15) ]
__global__ void conv_vt2(const float* __restrict__ vin, unsigned short* __restrict__ vt2) {
    int tid  = blockIdx.x * 256 + threadIdx.x;  // 262144 total
    int lane = tid & 63;
    int blk  = tid >> 6;
    int nb = blk & 31;
    int pb = blk >> 5;
    int p0 = pb * 32 + ((lane >> 4) << 3);
    int n  = nb * 16 + (lane & 15);
    ushort4 a, b;
    a.x = (unsigned short)f2bf(vin[(p0 + 0) * DDIM + n]);
    a.y = (unsigned short)f2bf(vin[(p0 + 1) * DDIM + n]);
    a.z = (unsigned short)f2bf(vin[(p0 + 2) * DDIM + n]);
    a.w = (unsigned short)f2bf(vin[(p0 + 3) * DDIM + n]);
    b.x = (unsigned short)f2bf(vin[(p0 + 4) * DDIM + n]);
    b.y = (unsigned short)f2bf(vin[(p0 + 5) * DDIM + n]);
    b.z = (unsigned short)f2bf(vin[(p0 + 6) * DDIM + n]);
    b.w = (unsigned short)f2bf(vin[(p0 + 7) * DDIM + n]);
    *reinterpret_cast<ushort4*>(vt2 + tid * 8 + 0) = a;
    *reinterpret_cast<ushort4*>(vt2 + tid * 8 + 4) = b;
}

// ---------- fused kernel: 256 blocks x 384 threads (2 A-waves + 4 B-waves) ----------
__global__ __launch_bounds__(384, 1) void fused_pattn(
    const float* __restrict__ x,              // [16384][512] fp32
    const unsigned short* __restrict__ kbf,   // [4096][512] bf16 row-major
    const unsigned short* __restrict__ vt2,   // fragment-blocked bf16
    float* __restrict__ out)                  // [16384][512] fp32
{
    // k_lds: LINEAR [64][512] bf16 per buffer; chunk c of row r holds global chunk
    // c ^ (r&7) (source-pre-swizzled DMA).
    __shared__ unsigned short k_lds[2][BP * DDIM];   // 2 x 65536 B
    __shared__ unsigned short g_lds[2][BM * GPAD];   // 2 x  9216 B
    __shared__ float ss_lds[BM];                     // 256 B   (~150 KB)

    const int tid  = threadIdx.x;
    const int lane = tid & 63;
    const int w    = tid >> 6;       // wave 0..5
    const int l15  = lane & 15;
    const int l4   = lane >> 4;
    const int m_base = blockIdx.x * BM;

    if (w < 2) {
        // ========== TEAM A: GEMM1 (swapped -> S^T) + GELU + K staging ==========
        // Wave w owns m-rows [w*32, w*32+32), all 64 p. X in AGPR (2 x 16 frags).

        // prologue: stage k(0). Wave stages 32 rows: r = w*32 + i.
        #pragma unroll
        for (int i = 0; i < 32; ++i) {
            int r = w * 32 + i;
            const unsigned short* src = kbf + (size_t)r * DDIM + ((lane ^ (i & 7)) << 3);
            __builtin_amdgcn_global_load_lds(AS1C(src), AS3(&k_lds[0][r * DDIM]), 16, 0, 0);
        }

        // load X fragments: X[w*32 + mb*16 + l15][db*32 + l4*8 + j], packed bf16 pairs.
        i32x4 xa0[16], xa1[16];
        #pragma unroll
        for (int mb = 0; mb < 2; ++mb) {
            const float* xrow = x + (size_t)(m_base + w * 32 + mb * 16 + l15) * DDIM + l4 * 8;
            #pragma unroll
            for (int db = 0; db < 16; ++db) {
                float4 a  = *reinterpret_cast<const float4*>(xrow + db * 32);
                float4 bq = *reinterpret_cast<const float4*>(xrow + db * 32 + 4);
                i32x4 f;
                f[0] = (int)(f2bf(a.x)  | (f2bf(a.y)  << 16));
                f[1] = (int)(f2bf(a.z)  | (f2bf(a.w)  << 16));
                f[2] = (int)(f2bf(bq.x) | (f2bf(bq.y) << 16));
                f[3] = (int)(f2bf(bq.z) | (f2bf(bq.w) << 16));
                if (mb == 0) xa0[db] = f; else xa1[db] = f;
            }
        }
        asm volatile("s_waitcnt vmcnt(0)" ::: "memory");
        __builtin_amdgcn_s_barrier();                       // bar_0

        f32x4 zero4 = {0.0f, 0.0f, 0.0f, 0.0f};
        float ss[2] = {0.0f, 0.0f};   // lane-local sum g^2, m = w*32 + mb*16 + l15
        const int swz = (l15 & 7) << 3;

        #pragma unroll 1
        for (int t = 0; t < NSLOT; ++t) {
            // issue stage(t+1) into other buffer (wraps on last iter; harmless)
            {
                const int P0n = ((t + 1) & (NSLOT - 1)) * BP;
                #pragma unroll
                for (int i = 0; i < 32; ++i) {
                    int r = w * 32 + i;
                    const unsigned short* src =
                        kbf + (size_t)(P0n + r) * DDIM + ((lane ^ (i & 7)) << 3);
                    __builtin_amdgcn_global_load_lds(
                        AS1C(src), AS3(&k_lds[(t + 1) & 1][r * DDIM]), 16, 0, 0);
                }
            }

            // GEMM1 swapped: sacc[mb][pf] = S^T (p = pf*16+l4*4+r, m = w*32+mb*16+l15)
            // One kv read feeds 2 MFMAs (mb=0,1).
            f32x4 sacc[2][4];
            #pragma unroll
            for (int mb = 0; mb < 2; ++mb)
                #pragma unroll
                for (int pf = 0; pf < 4; ++pf) sacc[mb][pf] = zero4;
            const unsigned short* kb = &k_lds[t & 1][0];
            __builtin_amdgcn_s_setprio(1);
            #pragma unroll
            for (int db = 0; db < 16; ++db) {
                int cole = ((db << 5) | (l4 << 3)) ^ swz;
                i32x4 kv0 = *reinterpret_cast<const i32x4*>(kb + (l15)      * DDIM + cole);
                i32x4 kv1 = *reinterpret_cast<const i32x4*>(kb + (16 + l15) * DDIM + cole);
                i32x4 kv2 = *reinterpret_cast<const i32x4*>(kb + (32 + l15) * DDIM + cole);
                i32x4 kv3 = *reinterpret_cast<const i32x4*>(kb + (48 + l15) * DDIM + cole);
                mfma_av(sacc[0][0], kv0, xa0[db]);  mfma_av(sacc[1][0], kv0, xa1[db]);
                mfma_av(sacc[0][1], kv1, xa0[db]);  mfma_av(sacc[1][1], kv1, xa1[db]);
                mfma_av(sacc[0][2], kv2, xa0[db]);  mfma_av(sacc[1][2], kv2, xa1[db]);
                mfma_av(sacc[0][3], kv3, xa0[db]);  mfma_av(sacc[1][3], kv3, xa1[db]);
            }
            __builtin_amdgcn_s_setprio(0);

            // GELU + lane-local sumsq + packed b64 g-writes into g_lds[t&1]
            unsigned short* gb = &g_lds[t & 1][0];
            #pragma unroll
            for (int mb = 0; mb < 2; ++mb) {
                const int m_l = w * 32 + mb * 16 + l15;
                #pragma unroll
                for (int pf = 0; pf < 4; ++pf) {
                    float g0 = gelu_f(sacc[mb][pf][0]);
                    float g1 = gelu_f(sacc[mb][pf][1]);
                    float g2 = gelu_f(sacc[mb][pf][2]);
                    float g3 = gelu_f(sacc[mb][pf][3]);
                    ss[mb] += g0 * g0 + g1 * g1 + g2 * g2 + g3 * g3;
                    unsigned d0 = f2bf(g0) | (f2bf(g1) << 16);
                    unsigned d1 = f2bf(g2) | (f2bf(g3) << 16);
                    int p_l = pf * 16 + l4 * 4;
                    *reinterpret_cast<uint2*>(&gb[m_l * GPAD + p_l]) = make_uint2(d0, d1);
                }
            }
            asm volatile("s_waitcnt lgkmcnt(0)" ::: "memory");
            asm volatile("s_waitcnt vmcnt(0)" ::: "memory");   // own stage(t+1) landed
            __builtin_amdgcn_s_barrier();                       // bar_{t+1}
        }

        // sumsq: reduce the 4 l4-groups sharing each row; single writer per row.
        #pragma unroll
        for (int mb = 0; mb < 2; ++mb) {
            float v = ss[mb];
            v += __shfl_xor(v, 16, 64);
            v += __shfl_xor(v, 32, 64);
            if (l4 == 0) ss_lds[w * 32 + mb * 16 + l15] = v;
        }
        asm volatile("s_waitcnt lgkmcnt(0)" ::: "memory");
        __builtin_amdgcn_s_barrier();                           // bar_{NSLOT+1}
        // Team A done.
    } else {
        // ================= TEAM B: GEMM2 + epilogue (r6 verbatim) =================
        const int bw = w - 2;        // owns output cols [bw*128, bw*128+128)

        // prologue: prefetch bg(0): 16 x b128 V fragments
        bf16x8 bg[16];
        #pragma unroll
        for (int ks = 0; ks < 2; ++ks)
            #pragma unroll
            for (int nf = 0; nf < 8; ++nf)
                bg[ks * 8 + nf] = *reinterpret_cast<const bf16x8*>(
                    vt2 + ((size_t)(ks * 32 + bw * 8 + nf) * 64 + lane) * 8);

        f32x4 zero4 = {0.0f, 0.0f, 0.0f, 0.0f};
        f32x4 oacc[4][8];
        #pragma unroll
        for (int i = 0; i < 4; ++i)
            #pragma unroll
            for (int j = 0; j < 8; ++j) oacc[i][j] = zero4;

        __builtin_amdgcn_s_barrier();                           // bar_0

        #pragma unroll 1
        for (int t = 0; t < NSLOT; ++t) {
            __builtin_amdgcn_s_barrier();                       // bar_{t+1}: g(t) ready

            const unsigned short* gb = &g_lds[t & 1][0];
            __builtin_amdgcn_s_setprio(1);
            #pragma unroll
            for (int ks = 0; ks < 2; ++ks) {
                bf16x8 ag[4];
                #pragma unroll
                for (int mf = 0; mf < 4; ++mf)
                    ag[mf] = *reinterpret_cast<const bf16x8*>(
                        &gb[(mf * 16 + l15) * GPAD + ks * 32 + l4 * 8]);
                #pragma unroll
                for (int mf = 0; mf < 4; ++mf)
                    #pragma unroll
                    for (int nf = 0; nf < 8; ++nf)
                        oacc[mf][nf] = __builtin_amdgcn_mfma_f32_16x16x32_bf16(
                            ag[mf], bg[ks * 8 + nf], oacc[mf][nf], 0, 0, 0);
            }
            __builtin_amdgcn_s_setprio(0);

            // prefetch bg(t+1) (wraps on last iter; harmless); latency absorbed by
            // the next barrier wait; compiler inserts the use-waits.
            {
                const int pb0 = ((t + 1) & (NSLOT - 1)) * 2;
                #pragma unroll
                for (int ks = 0; ks < 2; ++ks)
                    #pragma unroll
                    for (int nf = 0; nf < 8; ++nf)
                        bg[ks * 8 + nf] = *reinterpret_cast<const bf16x8*>(
                            vt2 + ((size_t)((pb0 + ks) * 32 + bw * 8 + nf) * 64 + lane) * 8);
            }
        }

        __builtin_amdgcn_s_barrier();                           // bar_{NSLOT+1}: ss ready

        // epilogue: out = O * sqrt(P)/sqrt(ss)
        #pragma unroll
        for (int mf = 0; mf < 4; ++mf) {
            #pragma unroll
            for (int r = 0; r < 4; ++r) {
                int m_l = mf * 16 + l4 * 4 + r;
                float scale = 64.0f * rsqrtf(ss_lds[m_l]);
                float* orow = out + (size_t)(m_base + m_l) * DDIM + bw * 128 + l15;
                #pragma unroll
                for (int nf = 0; nf < 8; ++nf)
                    orow[nf * 16] = oacc[mf][nf][r] * scale;
            }
        }
    }
}

extern "C" void kernel_launch(void* const* d_in, const int* in_sizes, int n_in,
                              void* d_out, int out_size, void* d_ws, size_t ws_size,
                              hipStream_t stream) {
    const float* x = (const float*)d_in[0];   // [4,4096,512] = [16384][512]
    const float* k = (const float*)d_in[1];   // [4096][512]
    const float* v = (const float*)d_in[2];   // [4096][512]
    float* out = (float*)d_out;               // [16384][512]

    unsigned short* kbf = (unsigned short*)d_ws;            // 4 MB
    unsigned short* vt2 = kbf + (size_t)PDIM * DDIM;        // 4 MB

    conv_k  <<<dim3(2048), dim3(256), 0, stream>>>(k, kbf);
    conv_vt2<<<dim3(1024), dim3(256), 0, stream>>>(v, vt2);
    fused_pattn<<<dim3(M_TOTAL / BM), dim3(384), 0, stream>>>(x, kbf, vt2, out);
}